// Round 2
// baseline (362.302 us; speedup 1.0000x reference)
//
#include <hip/hip_runtime.h>

// Causal GQA prefill attention, flash-style, bf16 MFMA / fp32 softmax.
// B=2, S=2048, H=32, HKV=8, D=128, G=4.
// Prepass 1: K fp32 -> Kbf bf16 [b][hkv][S][D]      (d_ws +0,   8 MB)
// Prepass 2: V fp32 -> Vt  bf16 [b][hkv][D][S]      (d_ws +8MB, 8 MB)
// Main: 1024 blocks = 16 causal pairs (qb=x, qb=31-x) x 64 bh.
// Round 2 (this): VALU-bound fix per rocprof (VALUBusy 63%, MfmaUtil 15%):
//   - defer-max (THR=8, log2 domain): skip rowmax16 + alpha + acc-rescale
//     when tile max <= mrow+8 in all lanes (wave-uniform __all branch)
//   - lane-partial l-sum: rowsum16 moved out of the loop to the epilogue
//   - P/Q bf16 pack via (__bf16) casts -> compiler emits v_cvt_pk_bf16_f32
//     (manual f2bf RNE was ~4 VALU/value)

#define B_   2
#define S_   2048
#define H_   32
#define HKV_ 8
#define D_   128
#define SCALEF 0.08838834764831845f
#define COEF  (SCALEF * 1.44269504088896340736f)   // scale * log2(e)
#define DEFER_THR 8.0f                             // log2-domain defer-max

typedef float          f32x4 __attribute__((ext_vector_type(4)));
typedef __bf16         bf16x2 __attribute__((ext_vector_type(2)));
typedef __bf16         bf16x8 __attribute__((ext_vector_type(8)));
typedef unsigned short u16x8 __attribute__((ext_vector_type(8)));

#define MFMA16(a, b, c) __builtin_amdgcn_mfma_f32_16x16x32_bf16((a), (b), (c), 0, 0, 0)

#if defined(__has_builtin)
#if __has_builtin(__builtin_amdgcn_exp2f)
#define EXP2F(x) __builtin_amdgcn_exp2f(x)
#endif
#endif
#ifndef EXP2F
#define EXP2F(x) exp2f(x)
#endif

static __device__ __forceinline__ unsigned short f2bf(float f) {
  unsigned int u = __builtin_bit_cast(unsigned int, f);
  u = (u + 0x7fffu + ((u >> 16) & 1u)) >> 16;   // RNE; inputs finite
  return (unsigned short)u;
}

// async global->LDS, 16B per lane; lds dest = wave-uniform base + lane*16.
static __device__ __forceinline__ void load_lds16(const void* g, void* l) {
  __builtin_amdgcn_global_load_lds(
      (const __attribute__((address_space(1))) void*)g,
      (__attribute__((address_space(3))) void*)l, 16, 0, 0);
}

// DPP move (VALU pipe). CTRL: row_ror:n = 0x120|n, quad_perm[1,0,3,2] = 0xB1.
template <int CTRL>
static __device__ __forceinline__ float dppf(float v) {
  return __builtin_bit_cast(
      float, __builtin_amdgcn_update_dpp(0, __builtin_bit_cast(int, v), CTRL,
                                         0xF, 0xF, true));
}
static __device__ __forceinline__ float rowmax16(float v) {
  v = fmaxf(v, dppf<0x128>(v));
  v = fmaxf(v, dppf<0x124>(v));
  v = fmaxf(v, dppf<0x122>(v));
  v = fmaxf(v, dppf<0x121>(v));
  return v;
}
static __device__ __forceinline__ float rowsum16(float v) {
  v += dppf<0x128>(v);
  v += dppf<0x124>(v);
  v += dppf<0x122>(v);
  v += dppf<0x121>(v);
  return v;
}

// ------------- Prepass 1: K fp32 -> bf16 [b][hkv][S][D] -------------
__global__ __launch_bounds__(256) void k_convert_kernel(
    const float* __restrict__ k, unsigned short* __restrict__ kbf) {
  int t = blockIdx.x * 256 + threadIdx.x;
  int o = t * 8;                       // output-linear index
  int d = o & (D_ - 1);
  int s = (o >> 7) & (S_ - 1);
  int bh = o >> 18;                    // 0..15
  int b = bh >> 3, hkv = bh & 7;
  const float* src = k + (size_t)(b * S_ + s) * (HKV_ * D_) + hkv * D_ + d;
  f32x4 x0 = *(const f32x4*)src;
  f32x4 x1 = *(const f32x4*)(src + 4);
  u16x8 w;
  w[0] = f2bf(x0[0]); w[1] = f2bf(x0[1]); w[2] = f2bf(x0[2]); w[3] = f2bf(x0[3]);
  w[4] = f2bf(x1[0]); w[5] = f2bf(x1[1]); w[6] = f2bf(x1[2]); w[7] = f2bf(x1[3]);
  *(u16x8*)(kbf + o) = w;
}

// ------------- Prepass 2: V -> Vt (bf16, [b][hkv][D][S]) -------------
__global__ __launch_bounds__(256) void vt_transpose_kernel(
    const float* __restrict__ v, unsigned short* __restrict__ vt) {
  __shared__ float tile[32][65];  // +1 pad: conflict-free
  const int tid = threadIdx.x;
  const int s0 = blockIdx.x * 64;   // 32 s-tiles
  const int d0 = blockIdx.y * 32;   // 4 d-tiles
  const int bh = blockIdx.z;        // 16 (b*8+hkv)
  const float* src = v + (size_t)(bh >> 3) * S_ * (HKV_ * D_) + (bh & 7) * D_;
#pragma unroll
  for (int it = 0; it < 8; ++it) {
    int idx = it * 256 + tid;
    int sl = idx >> 5, dl = idx & 31;  // coalesced along d
    tile[dl][sl] = src[(size_t)(s0 + sl) * (HKV_ * D_) + d0 + dl];
  }
  __syncthreads();
  unsigned int* dst = (unsigned int*)vt;
#pragma unroll
  for (int it = 0; it < 4; ++it) {
    int idx = it * 256 + tid;
    int dl = idx >> 5, sp = idx & 31;
    unsigned int w = (unsigned int)f2bf(tile[dl][2 * sp]) |
                     ((unsigned int)f2bf(tile[dl][2 * sp + 1]) << 16);
    dst[(((size_t)bh * D_ + d0 + dl) * S_ + s0 + 2 * sp) >> 1] = w;
  }
}

// ------------- Main attention kernel -------------
#define PSTR 40  // PL row stride in shorts (80 B, 16B-aligned, 2-way banks)

__global__ __launch_bounds__(256, 4) void attn_kernel(
    const float* __restrict__ qg, const unsigned short* __restrict__ kbfg,
    const unsigned short* __restrict__ vtg, float* __restrict__ outg) {
  __shared__ unsigned short KL[2][32 * 128];   // 2 x 8 KB
  __shared__ unsigned short VL[2][128 * 32];   // 2 x 8 KB (chunk-swizzled)
  __shared__ unsigned short PL[4][16 * PSTR];  // 4 x 1.25 KB (per-wave P)

  const int tid = threadIdx.x;
  const int wave = tid >> 6, lane = tid & 63;
  const int l15 = lane & 15, quad = lane >> 4;

  const int xb = (int)blockIdx.x;  // 0..15: handles qb = xb and qb = 31-xb
  const int b = (int)(blockIdx.y >> 5), h = (int)(blockIdx.y & 31);
  const int hkv = h >> 2;

  const unsigned short* kbf = kbfg + (size_t)(b * HKV_ + hkv) * S_ * D_;
  const unsigned short* vtb = vtg + (size_t)(b * HKV_ + hkv) * D_ * S_;

  const f32x4 zero4 = {0.f, 0.f, 0.f, 0.f};
  const float NEG_INF = -__builtin_huge_valf();

  // ---- async staging of one K/Vt tile pair into buffer `buf` ----
  // K chunk swizzle: phys chunk pc of row kr holds logical pc^(kr&15).
  // V chunk swizzle: phys chunk pc of row dr holds logical pc^((dr>>1)&3).
  auto stage = [&](int kt, int buf) {
#pragma unroll
    for (int j = 0; j < 2; ++j) {
      int si = wave * 128 + j * 64 + lane;
      int kr = si >> 4, pc = si & 15;
      int lc = pc ^ (kr & 15);
      load_lds16(kbf + (size_t)(kt * 32 + kr) * D_ + lc * 8,
                 &KL[buf][(wave * 128 + j * 64) * 8]);
    }
#pragma unroll
    for (int j = 0; j < 2; ++j) {
      int si = wave * 128 + j * 64 + lane;
      int dr = si >> 2, pc = si & 3;
      int lc = pc ^ ((dr >> 1) & 3);
      load_lds16(vtb + (size_t)dr * S_ + kt * 32 + lc * 8,
                 &VL[buf][(wave * 128 + j * 64) * 8]);
    }
  };

  for (int ph = 0; ph < 2; ++ph) {
    const int qb = ph ? (31 - xb) : xb;
    const int qbase = qb * 64 + wave * 16;  // this wave's 16 q rows

    // Q fragments (A-layout), pre-scaled by COEF -> exp arg = 1 subtract.
    bf16x8 qf[4];
#pragma unroll
    for (int ch = 0; ch < 4; ++ch) {
      const float* p = qg + (size_t)(b * S_ + qbase + l15) * (H_ * D_) +
                       h * D_ + ch * 32 + quad * 8;
      f32x4 x0 = *(const f32x4*)p;
      f32x4 x1 = *(const f32x4*)(p + 4);
      bf16x8 t;
      t[0] = (__bf16)(x0[0] * COEF); t[1] = (__bf16)(x0[1] * COEF);
      t[2] = (__bf16)(x0[2] * COEF); t[3] = (__bf16)(x0[3] * COEF);
      t[4] = (__bf16)(x1[0] * COEF); t[5] = (__bf16)(x1[1] * COEF);
      t[6] = (__bf16)(x1[2] * COEF); t[7] = (__bf16)(x1[3] * COEF);
      qf[ch] = t;
    }

    f32x4 acc[8];
#pragma unroll
    for (int dt = 0; dt < 8; ++dt) acc[dt] = zero4;
    f32x4 mrow = {NEG_INF, NEG_INF, NEG_INF, NEG_INF};
    f32x4 lsum = zero4;  // lane-partial row sum; reduced once in epilogue

    const int nkt = qb * 2 + 2;  // always even

    stage(0, 0);
    __syncthreads();  // drains vmcnt: tile 0 resident

    for (int kt = 0; kt < nkt; ++kt) {
      const int cur = kt & 1;
      if (kt + 1 < nkt) stage(kt + 1, cur ^ 1);  // async, lands under compute

      if (kt * 32 <= qbase + 15) {  // wave-uniform: skip fully-masked tiles
        // ---- QK^T: 16 q-rows x 32 k-cols (log2-domain scores) ----
        f32x4 sc[2] = {zero4, zero4};
#pragma unroll
        for (int h2 = 0; h2 < 2; ++h2) {
          const int row = h2 * 16 + l15;
#pragma unroll
          for (int ch = 0; ch < 4; ++ch) {
            const int pc = (ch * 4 + quad) ^ l15;  // un-swizzle
            u16x8 kf = *(const u16x8*)&KL[cur][row * D_ + pc * 8];
            sc[h2] = MFMA16(qf[ch], __builtin_bit_cast(bf16x8, kf), sc[h2]);
          }
        }
        const int kb0 = kt * 32;
        // causal mask (boundary tiles only)
#pragma unroll
        for (int h2 = 0; h2 < 2; ++h2) {
          if (kb0 + h2 * 16 + 15 > qbase) {
            int kgp = kb0 + h2 * 16 + l15;
#pragma unroll
            for (int r = 0; r < 4; ++r) {
              int qgp = qbase + quad * 4 + r;
              if (kgp > qgp) sc[h2][r] = NEG_INF;
            }
          }
        }
        // ---- online softmax: defer-max fast path (T13) ----
        // lane-local tile max; defer when tile max <= mrow + THR everywhere.
        f32x4 lmax;
        int fastok = 1;
#pragma unroll
        for (int r = 0; r < 4; ++r) {
          lmax[r] = fmaxf(sc[0][r], sc[1][r]);
          fastok &= (lmax[r] <= mrow[r] + DEFER_THR) ? 1 : 0;
        }
        if (__all(fastok)) {
          // m unchanged: no rowmax16, no alpha, no acc rescale.
          // P bounded by 2^THR = 256; fp32 accum tolerates.
#pragma unroll
          for (int r = 0; r < 4; ++r) {
            float p0 = EXP2F(sc[0][r] - mrow[r]);
            float p1 = EXP2F(sc[1][r] - mrow[r]);
            sc[0][r] = p0;
            sc[1][r] = p1;
            lsum[r] += p0 + p1;
          }
        } else {
          f32x4 mold = mrow, al;
#pragma unroll
          for (int r = 0; r < 4; ++r) {
            float mt = rowmax16(lmax[r]);
            float mn = fmaxf(mold[r], mt);
            mrow[r] = mn;
            al[r] = EXP2F(mold[r] - mn);
            float p0 = EXP2F(sc[0][r] - mn);
            float p1 = EXP2F(sc[1][r] - mn);
            sc[0][r] = p0;
            sc[1][r] = p1;
            lsum[r] = lsum[r] * al[r] + (p0 + p1);
          }
#pragma unroll
          for (int dt = 0; dt < 8; ++dt)
#pragma unroll
            for (int r = 0; r < 4; ++r) acc[dt][r] *= al[r];
        }
        // P: C-layout -> LDS bf16 (even lanes pack (k,k+1) via quad_perm);
        // (__bf16) casts -> v_cvt_pk_bf16_f32 (1 op/pair vs ~8 manual).
#pragma unroll
        for (int h2 = 0; h2 < 2; ++h2)
#pragma unroll
          for (int r = 0; r < 4; ++r) {
            float mine = sc[h2][r];
            float nb = dppf<0xB1>(mine);  // value from lane^1
            if (!(l15 & 1)) {
              bf16x2 pk;
              pk[0] = (__bf16)mine;
              pk[1] = (__bf16)nb;
              *(bf16x2*)&PL[wave][(quad * 4 + r) * PSTR + h2 * 16 + l15] = pk;
            }
          }
        // ---- PV: A = P (A-layout from LDS), B = Vt (swizzled chunks) ----
        u16x8 pf = *(const u16x8*)&PL[wave][l15 * PSTR + quad * 8];
        bf16x8 pb = __builtin_bit_cast(bf16x8, pf);
        const int vsw = (quad ^ ((l15 >> 1) & 3)) * 8;  // un-swizzle V chunk
#pragma unroll
        for (int dt = 0; dt < 8; ++dt) {
          u16x8 vf = *(const u16x8*)&VL[cur][(dt * 16 + l15) * 32 + vsw];
          acc[dt] = MFMA16(pb, __builtin_bit_cast(bf16x8, vf), acc[dt]);
        }
      }
      __syncthreads();  // drains vmcnt (next tile resident) + publishes bufs
    }

    // ---- epilogue: reduce lane-partial sums once, O /= l, store fp32 ----
    f32x4 inv;
#pragma unroll
    for (int r = 0; r < 4; ++r) inv[r] = 1.0f / rowsum16(lsum[r]);
#pragma unroll
    for (int dt = 0; dt < 8; ++dt)
#pragma unroll
      for (int r = 0; r < 4; ++r)
        outg[(size_t)(b * S_ + qbase + quad * 4 + r) * (H_ * D_) +
             h * D_ + dt * 16 + l15] = acc[dt][r] * inv[r];
  }
}

extern "C" void kernel_launch(void* const* d_in, const int* in_sizes, int n_in,
                              void* d_out, int out_size, void* d_ws,
                              size_t ws_size, hipStream_t stream) {
  const float* q = (const float*)d_in[0];
  const float* k = (const float*)d_in[1];
  const float* v = (const float*)d_in[2];
  float* out = (float*)d_out;
  unsigned short* kws = (unsigned short*)d_ws;               // 8 MB Kbf
  unsigned short* vtws = kws + (size_t)B_ * HKV_ * S_ * D_;  // 8 MB Vt

  k_convert_kernel<<<(B_ * S_ * HKV_ * D_ / 8) / 256, 256, 0, stream>>>(k, kws);

  dim3 g1(S_ / 64, D_ / 32, B_ * HKV_);
  vt_transpose_kernel<<<g1, 256, 0, stream>>>(v, vtws);

  dim3 g2(16, B_ * H_);  // 16 x 64 = 1024 uniform blocks (68 k-iters each)
  attn_kernel<<<g2, 256, 0, stream>>>(q, kws, vtws, out);
}

// Round 3
// 241.030 us; speedup vs baseline: 1.5031x; 1.5031x over previous
//
#include <hip/hip_runtime.h>

// Causal GQA prefill attention, flash-style, bf16 MFMA / fp32 softmax.
// B=2, S=2048, H=32, HKV=8, D=128, G=4.
// Prepass 1: K fp32 -> Kbf bf16 [b][hkv][S][D]      (d_ws +0,   8 MB)
// Prepass 2: V fp32 -> Vt  bf16 [b][hkv][D][S]      (d_ws +8MB, 8 MB)
// Main: 1024 blocks = 16 causal pairs (qb=x, qb=31-x) x 64 bh.
// Round 3: round 2's defer-max regressed (FETCH 152->451 MB = scratch
//   spills: duplicated exp2 path in a divergent branch blew the 128-reg
//   budget at 4 waves/SIMD). This round keeps defer-max + lane-partial
//   lsum + cvt_pk casts but shares ONE exp2/P path after the branch; the
//   slow branch holds only rowmax/alpha/rescale. Fast-path gate is a
//   single scalar dmax (no live vectors across the branch).

#define B_   2
#define S_   2048
#define H_   32
#define HKV_ 8
#define D_   128
#define SCALEF 0.08838834764831845f
#define COEF  (SCALEF * 1.44269504088896340736f)   // scale * log2(e)
#define DEFER_THR 8.0f                             // log2-domain defer-max

typedef float          f32x4 __attribute__((ext_vector_type(4)));
typedef __bf16         bf16x2 __attribute__((ext_vector_type(2)));
typedef __bf16         bf16x8 __attribute__((ext_vector_type(8)));
typedef unsigned short u16x8 __attribute__((ext_vector_type(8)));

#define MFMA16(a, b, c) __builtin_amdgcn_mfma_f32_16x16x32_bf16((a), (b), (c), 0, 0, 0)

#if defined(__has_builtin)
#if __has_builtin(__builtin_amdgcn_exp2f)
#define EXP2F(x) __builtin_amdgcn_exp2f(x)
#endif
#endif
#ifndef EXP2F
#define EXP2F(x) exp2f(x)
#endif

static __device__ __forceinline__ unsigned short f2bf(float f) {
  unsigned int u = __builtin_bit_cast(unsigned int, f);
  u = (u + 0x7fffu + ((u >> 16) & 1u)) >> 16;   // RNE; inputs finite
  return (unsigned short)u;
}

// async global->LDS, 16B per lane; lds dest = wave-uniform base + lane*16.
static __device__ __forceinline__ void load_lds16(const void* g, void* l) {
  __builtin_amdgcn_global_load_lds(
      (const __attribute__((address_space(1))) void*)g,
      (__attribute__((address_space(3))) void*)l, 16, 0, 0);
}

// DPP move (VALU pipe). CTRL: row_ror:n = 0x120|n, quad_perm[1,0,3,2] = 0xB1.
template <int CTRL>
static __device__ __forceinline__ float dppf(float v) {
  return __builtin_bit_cast(
      float, __builtin_amdgcn_update_dpp(0, __builtin_bit_cast(int, v), CTRL,
                                         0xF, 0xF, true));
}
static __device__ __forceinline__ float rowmax16(float v) {
  v = fmaxf(v, dppf<0x128>(v));
  v = fmaxf(v, dppf<0x124>(v));
  v = fmaxf(v, dppf<0x122>(v));
  v = fmaxf(v, dppf<0x121>(v));
  return v;
}
static __device__ __forceinline__ float rowsum16(float v) {
  v += dppf<0x128>(v);
  v += dppf<0x124>(v);
  v += dppf<0x122>(v);
  v += dppf<0x121>(v);
  return v;
}

// ------------- Prepass 1: K fp32 -> bf16 [b][hkv][S][D] -------------
__global__ __launch_bounds__(256) void k_convert_kernel(
    const float* __restrict__ k, unsigned short* __restrict__ kbf) {
  int t = blockIdx.x * 256 + threadIdx.x;
  int o = t * 8;                       // output-linear index
  int d = o & (D_ - 1);
  int s = (o >> 7) & (S_ - 1);
  int bh = o >> 18;                    // 0..15
  int b = bh >> 3, hkv = bh & 7;
  const float* src = k + (size_t)(b * S_ + s) * (HKV_ * D_) + hkv * D_ + d;
  f32x4 x0 = *(const f32x4*)src;
  f32x4 x1 = *(const f32x4*)(src + 4);
  u16x8 w;
  w[0] = f2bf(x0[0]); w[1] = f2bf(x0[1]); w[2] = f2bf(x0[2]); w[3] = f2bf(x0[3]);
  w[4] = f2bf(x1[0]); w[5] = f2bf(x1[1]); w[6] = f2bf(x1[2]); w[7] = f2bf(x1[3]);
  *(u16x8*)(kbf + o) = w;
}

// ------------- Prepass 2: V -> Vt (bf16, [b][hkv][D][S]) -------------
__global__ __launch_bounds__(256) void vt_transpose_kernel(
    const float* __restrict__ v, unsigned short* __restrict__ vt) {
  __shared__ float tile[32][65];  // +1 pad: conflict-free
  const int tid = threadIdx.x;
  const int s0 = blockIdx.x * 64;   // 32 s-tiles
  const int d0 = blockIdx.y * 32;   // 4 d-tiles
  const int bh = blockIdx.z;        // 16 (b*8+hkv)
  const float* src = v + (size_t)(bh >> 3) * S_ * (HKV_ * D_) + (bh & 7) * D_;
#pragma unroll
  for (int it = 0; it < 8; ++it) {
    int idx = it * 256 + tid;
    int sl = idx >> 5, dl = idx & 31;  // coalesced along d
    tile[dl][sl] = src[(size_t)(s0 + sl) * (HKV_ * D_) + d0 + dl];
  }
  __syncthreads();
  unsigned int* dst = (unsigned int*)vt;
#pragma unroll
  for (int it = 0; it < 4; ++it) {
    int idx = it * 256 + tid;
    int dl = idx >> 5, sp = idx & 31;
    unsigned int w = (unsigned int)f2bf(tile[dl][2 * sp]) |
                     ((unsigned int)f2bf(tile[dl][2 * sp + 1]) << 16);
    dst[(((size_t)bh * D_ + d0 + dl) * S_ + s0 + 2 * sp) >> 1] = w;
  }
}

// ------------- Main attention kernel -------------
#define PSTR 40  // PL row stride in shorts (80 B, 16B-aligned, 2-way banks)

__global__ __launch_bounds__(256, 4) void attn_kernel(
    const float* __restrict__ qg, const unsigned short* __restrict__ kbfg,
    const unsigned short* __restrict__ vtg, float* __restrict__ outg) {
  __shared__ unsigned short KL[2][32 * 128];   // 2 x 8 KB
  __shared__ unsigned short VL[2][128 * 32];   // 2 x 8 KB (chunk-swizzled)
  __shared__ unsigned short PL[4][16 * PSTR];  // 4 x 1.25 KB (per-wave P)

  const int tid = threadIdx.x;
  const int wave = tid >> 6, lane = tid & 63;
  const int l15 = lane & 15, quad = lane >> 4;

  const int xb = (int)blockIdx.x;  // 0..15: handles qb = xb and qb = 31-xb
  const int b = (int)(blockIdx.y >> 5), h = (int)(blockIdx.y & 31);
  const int hkv = h >> 2;

  const unsigned short* kbf = kbfg + (size_t)(b * HKV_ + hkv) * S_ * D_;
  const unsigned short* vtb = vtg + (size_t)(b * HKV_ + hkv) * D_ * S_;

  const f32x4 zero4 = {0.f, 0.f, 0.f, 0.f};
  const float NEG_INF = -__builtin_huge_valf();

  // ---- async staging of one K/Vt tile pair into buffer `buf` ----
  // K chunk swizzle: phys chunk pc of row kr holds logical pc^(kr&15).
  // V chunk swizzle: phys chunk pc of row dr holds logical pc^((dr>>1)&3).
  auto stage = [&](int kt, int buf) {
#pragma unroll
    for (int j = 0; j < 2; ++j) {
      int si = wave * 128 + j * 64 + lane;
      int kr = si >> 4, pc = si & 15;
      int lc = pc ^ (kr & 15);
      load_lds16(kbf + (size_t)(kt * 32 + kr) * D_ + lc * 8,
                 &KL[buf][(wave * 128 + j * 64) * 8]);
    }
#pragma unroll
    for (int j = 0; j < 2; ++j) {
      int si = wave * 128 + j * 64 + lane;
      int dr = si >> 2, pc = si & 3;
      int lc = pc ^ ((dr >> 1) & 3);
      load_lds16(vtb + (size_t)dr * S_ + kt * 32 + lc * 8,
                 &VL[buf][(wave * 128 + j * 64) * 8]);
    }
  };

  for (int ph = 0; ph < 2; ++ph) {
    const int qb = ph ? (31 - xb) : xb;
    const int qbase = qb * 64 + wave * 16;  // this wave's 16 q rows

    // Q fragments (A-layout), pre-scaled by COEF -> exp arg = 1 subtract.
    bf16x8 qf[4];
#pragma unroll
    for (int ch = 0; ch < 4; ++ch) {
      const float* p = qg + (size_t)(b * S_ + qbase + l15) * (H_ * D_) +
                       h * D_ + ch * 32 + quad * 8;
      f32x4 x0 = *(const f32x4*)p;
      f32x4 x1 = *(const f32x4*)(p + 4);
      bf16x8 t;
      t[0] = (__bf16)(x0[0] * COEF); t[1] = (__bf16)(x0[1] * COEF);
      t[2] = (__bf16)(x0[2] * COEF); t[3] = (__bf16)(x0[3] * COEF);
      t[4] = (__bf16)(x1[0] * COEF); t[5] = (__bf16)(x1[1] * COEF);
      t[6] = (__bf16)(x1[2] * COEF); t[7] = (__bf16)(x1[3] * COEF);
      qf[ch] = t;
    }

    f32x4 acc[8];
#pragma unroll
    for (int dt = 0; dt < 8; ++dt) acc[dt] = zero4;
    f32x4 mrow = {NEG_INF, NEG_INF, NEG_INF, NEG_INF};
    f32x4 lsum = zero4;  // lane-partial row sum; reduced once in epilogue

    const int nkt = qb * 2 + 2;  // always even

    stage(0, 0);
    __syncthreads();  // drains vmcnt: tile 0 resident

    for (int kt = 0; kt < nkt; ++kt) {
      const int cur = kt & 1;
      if (kt + 1 < nkt) stage(kt + 1, cur ^ 1);  // async, lands under compute

      if (kt * 32 <= qbase + 15) {  // wave-uniform: skip fully-masked tiles
        // ---- QK^T: 16 q-rows x 32 k-cols (log2-domain scores) ----
        f32x4 sc[2] = {zero4, zero4};
#pragma unroll
        for (int h2 = 0; h2 < 2; ++h2) {
          const int row = h2 * 16 + l15;
#pragma unroll
          for (int ch = 0; ch < 4; ++ch) {
            const int pc = (ch * 4 + quad) ^ l15;  // un-swizzle
            u16x8 kf = *(const u16x8*)&KL[cur][row * D_ + pc * 8];
            sc[h2] = MFMA16(qf[ch], __builtin_bit_cast(bf16x8, kf), sc[h2]);
          }
        }
        const int kb0 = kt * 32;
        // causal mask (boundary tiles only)
#pragma unroll
        for (int h2 = 0; h2 < 2; ++h2) {
          if (kb0 + h2 * 16 + 15 > qbase) {
            int kgp = kb0 + h2 * 16 + l15;
#pragma unroll
            for (int r = 0; r < 4; ++r) {
              int qgp = qbase + quad * 4 + r;
              if (kgp > qgp) sc[h2][r] = NEG_INF;
            }
          }
        }
        // ---- online softmax: defer-max (T13), ONE shared exp path ----
        // scalar gate: dmax = max_r(tile_max_r - mrow_r). First tile
        // (mrow=-inf) gives inf/NaN -> comparison false -> slow path.
        {
          float a0 = fmaxf(sc[0][0], sc[1][0]) - mrow[0];
          float a1 = fmaxf(sc[0][1], sc[1][1]) - mrow[1];
          float a2 = fmaxf(sc[0][2], sc[1][2]) - mrow[2];
          float a3 = fmaxf(sc[0][3], sc[1][3]) - mrow[3];
          float dmax = fmaxf(fmaxf(a0, a1), fmaxf(a2, a3));
          if (!__all(dmax <= DEFER_THR)) {
            // slow path: refresh row max, rescale running state.
            f32x4 al;
#pragma unroll
            for (int r = 0; r < 4; ++r) {
              float mt = rowmax16(fmaxf(sc[0][r], sc[1][r]));
              float mn = fmaxf(mrow[r], mt);
              al[r] = EXP2F(mrow[r] - mn);
              mrow[r] = mn;
              lsum[r] *= al[r];
            }
#pragma unroll
            for (int dt = 0; dt < 8; ++dt)
#pragma unroll
              for (int r = 0; r < 4; ++r) acc[dt][r] *= al[r];
          }
        }
        // shared P computation (fast path: P bounded by 2^THR = 256).
#pragma unroll
        for (int r = 0; r < 4; ++r) {
          float p0 = EXP2F(sc[0][r] - mrow[r]);
          float p1 = EXP2F(sc[1][r] - mrow[r]);
          sc[0][r] = p0;
          sc[1][r] = p1;
          lsum[r] += p0 + p1;
        }
        // P: C-layout -> LDS bf16 (even lanes pack (k,k+1) via quad_perm);
        // (__bf16) casts -> v_cvt_pk_bf16_f32.
#pragma unroll
        for (int h2 = 0; h2 < 2; ++h2)
#pragma unroll
          for (int r = 0; r < 4; ++r) {
            float mine = sc[h2][r];
            float nb = dppf<0xB1>(mine);  // value from lane^1
            if (!(l15 & 1)) {
              bf16x2 pk;
              pk[0] = (__bf16)mine;
              pk[1] = (__bf16)nb;
              *(bf16x2*)&PL[wave][(quad * 4 + r) * PSTR + h2 * 16 + l15] = pk;
            }
          }
        // ---- PV: A = P (A-layout from LDS), B = Vt (swizzled chunks) ----
        u16x8 pf = *(const u16x8*)&PL[wave][l15 * PSTR + quad * 8];
        bf16x8 pb = __builtin_bit_cast(bf16x8, pf);
        const int vsw = (quad ^ ((l15 >> 1) & 3)) * 8;  // un-swizzle V chunk
#pragma unroll
        for (int dt = 0; dt < 8; ++dt) {
          u16x8 vf = *(const u16x8*)&VL[cur][(dt * 16 + l15) * 32 + vsw];
          acc[dt] = MFMA16(pb, __builtin_bit_cast(bf16x8, vf), acc[dt]);
        }
      }
      __syncthreads();  // drains vmcnt (next tile resident) + publishes bufs
    }

    // ---- epilogue: reduce lane-partial sums once, O /= l, store fp32 ----
    f32x4 inv;
#pragma unroll
    for (int r = 0; r < 4; ++r) inv[r] = 1.0f / rowsum16(lsum[r]);
#pragma unroll
    for (int dt = 0; dt < 8; ++dt)
#pragma unroll
      for (int r = 0; r < 4; ++r)
        outg[(size_t)(b * S_ + qbase + quad * 4 + r) * (H_ * D_) +
             h * D_ + dt * 16 + l15] = acc[dt][r] * inv[r];
  }
}

extern "C" void kernel_launch(void* const* d_in, const int* in_sizes, int n_in,
                              void* d_out, int out_size, void* d_ws,
                              size_t ws_size, hipStream_t stream) {
  const float* q = (const float*)d_in[0];
  const float* k = (const float*)d_in[1];
  const float* v = (const float*)d_in[2];
  float* out = (float*)d_out;
  unsigned short* kws = (unsigned short*)d_ws;               // 8 MB Kbf
  unsigned short* vtws = kws + (size_t)B_ * HKV_ * S_ * D_;  // 8 MB Vt

  k_convert_kernel<<<(B_ * S_ * HKV_ * D_ / 8) / 256, 256, 0, stream>>>(k, kws);

  dim3 g1(S_ / 64, D_ / 32, B_ * HKV_);
  vt_transpose_kernel<<<g1, 256, 0, stream>>>(v, vtws);

  dim3 g2(16, B_ * H_);  // 16 x 64 = 1024 uniform blocks (68 k-iters each)
  attn_kernel<<<g2, 256, 0, stream>>>(q, kws, vtws, out);
}

// Round 4
// 240.856 us; speedup vs baseline: 1.5042x; 1.0007x over previous
//
#include <hip/hip_runtime.h>

// Causal GQA prefill attention, flash-style, bf16 MFMA / fp32 softmax.
// B=2, S=2048, H=32, HKV=8, D=128, G=4.
// Prepass 1: K fp32 -> Kbf bf16 [b][hkv][S][D]      (d_ws +0,   8 MB)
// Prepass 2: V fp32 -> Vt  bf16 [b][hkv][D][S]      (d_ws +8MB, 8 MB)
// Main: 1024 blocks = 16 causal pairs (qb=x, qb=31-x) x 64 bh.
// Round 3: defer-max (shared exp path, scalar gate) -> attn 139 us,
//   VALUBusy 41.6, MfmaUtil 21.3. Reg budget at (256,4) is 128/wave and
//   we sit at 64 VGPR + 64 AGPR: NO headroom (round 2 spilled).
// Round 4 (this): per-iter overhead cuts, no structural change:
//   - k-loop unrolled x2 with LITERAL cur -> KL/VL bases become
//     compile-time LDS offsets (addr chains CSE across iters)
//   - s_setprio(1) around QK^T and PV MFMA clusters (T5, m191 +4-7%)
//   - cheaper gate: mmin = min_r(mrow) kept incrementally (slow path
//     only); fast gate = max8(sc) <= mmin+THR (7 fmax -> max3 pairs)

#define B_   2
#define S_   2048
#define H_   32
#define HKV_ 8
#define D_   128
#define SCALEF 0.08838834764831845f
#define COEF  (SCALEF * 1.44269504088896340736f)   // scale * log2(e)
#define DEFER_THR 8.0f                             // log2-domain defer-max

typedef float          f32x4 __attribute__((ext_vector_type(4)));
typedef __bf16         bf16x2 __attribute__((ext_vector_type(2)));
typedef __bf16         bf16x8 __attribute__((ext_vector_type(8)));
typedef unsigned short u16x8 __attribute__((ext_vector_type(8)));

#define MFMA16(a, b, c) __builtin_amdgcn_mfma_f32_16x16x32_bf16((a), (b), (c), 0, 0, 0)

#if defined(__has_builtin)
#if __has_builtin(__builtin_amdgcn_exp2f)
#define EXP2F(x) __builtin_amdgcn_exp2f(x)
#endif
#endif
#ifndef EXP2F
#define EXP2F(x) exp2f(x)
#endif

static __device__ __forceinline__ unsigned short f2bf(float f) {
  unsigned int u = __builtin_bit_cast(unsigned int, f);
  u = (u + 0x7fffu + ((u >> 16) & 1u)) >> 16;   // RNE; inputs finite
  return (unsigned short)u;
}

// async global->LDS, 16B per lane; lds dest = wave-uniform base + lane*16.
static __device__ __forceinline__ void load_lds16(const void* g, void* l) {
  __builtin_amdgcn_global_load_lds(
      (const __attribute__((address_space(1))) void*)g,
      (__attribute__((address_space(3))) void*)l, 16, 0, 0);
}

// DPP move (VALU pipe). CTRL: row_ror:n = 0x120|n, quad_perm[1,0,3,2] = 0xB1.
template <int CTRL>
static __device__ __forceinline__ float dppf(float v) {
  return __builtin_bit_cast(
      float, __builtin_amdgcn_update_dpp(0, __builtin_bit_cast(int, v), CTRL,
                                         0xF, 0xF, true));
}
static __device__ __forceinline__ float rowmax16(float v) {
  v = fmaxf(v, dppf<0x128>(v));
  v = fmaxf(v, dppf<0x124>(v));
  v = fmaxf(v, dppf<0x122>(v));
  v = fmaxf(v, dppf<0x121>(v));
  return v;
}
static __device__ __forceinline__ float rowsum16(float v) {
  v += dppf<0x128>(v);
  v += dppf<0x124>(v);
  v += dppf<0x122>(v);
  v += dppf<0x121>(v);
  return v;
}

// ------------- Prepass 1: K fp32 -> bf16 [b][hkv][S][D] -------------
__global__ __launch_bounds__(256) void k_convert_kernel(
    const float* __restrict__ k, unsigned short* __restrict__ kbf) {
  int t = blockIdx.x * 256 + threadIdx.x;
  int o = t * 8;                       // output-linear index
  int d = o & (D_ - 1);
  int s = (o >> 7) & (S_ - 1);
  int bh = o >> 18;                    // 0..15
  int b = bh >> 3, hkv = bh & 7;
  const float* src = k + (size_t)(b * S_ + s) * (HKV_ * D_) + hkv * D_ + d;
  f32x4 x0 = *(const f32x4*)src;
  f32x4 x1 = *(const f32x4*)(src + 4);
  u16x8 w;
  w[0] = f2bf(x0[0]); w[1] = f2bf(x0[1]); w[2] = f2bf(x0[2]); w[3] = f2bf(x0[3]);
  w[4] = f2bf(x1[0]); w[5] = f2bf(x1[1]); w[6] = f2bf(x1[2]); w[7] = f2bf(x1[3]);
  *(u16x8*)(kbf + o) = w;
}

// ------------- Prepass 2: V -> Vt (bf16, [b][hkv][D][S]) -------------
__global__ __launch_bounds__(256) void vt_transpose_kernel(
    const float* __restrict__ v, unsigned short* __restrict__ vt) {
  __shared__ float tile[32][65];  // +1 pad: conflict-free
  const int tid = threadIdx.x;
  const int s0 = blockIdx.x * 64;   // 32 s-tiles
  const int d0 = blockIdx.y * 32;   // 4 d-tiles
  const int bh = blockIdx.z;        // 16 (b*8+hkv)
  const float* src = v + (size_t)(bh >> 3) * S_ * (HKV_ * D_) + (bh & 7) * D_;
#pragma unroll
  for (int it = 0; it < 8; ++it) {
    int idx = it * 256 + tid;
    int sl = idx >> 5, dl = idx & 31;  // coalesced along d
    tile[dl][sl] = src[(size_t)(s0 + sl) * (HKV_ * D_) + d0 + dl];
  }
  __syncthreads();
  unsigned int* dst = (unsigned int*)vt;
#pragma unroll
  for (int it = 0; it < 4; ++it) {
    int idx = it * 256 + tid;
    int dl = idx >> 5, sp = idx & 31;
    unsigned int w = (unsigned int)f2bf(tile[dl][2 * sp]) |
                     ((unsigned int)f2bf(tile[dl][2 * sp + 1]) << 16);
    dst[(((size_t)bh * D_ + d0 + dl) * S_ + s0 + 2 * sp) >> 1] = w;
  }
}

// ------------- Main attention kernel -------------
#define PSTR 40  // PL row stride in shorts (80 B, 16B-aligned, 2-way banks)

__global__ __launch_bounds__(256, 4) void attn_kernel(
    const float* __restrict__ qg, const unsigned short* __restrict__ kbfg,
    const unsigned short* __restrict__ vtg, float* __restrict__ outg) {
  __shared__ unsigned short KL[2][32 * 128];   // 2 x 8 KB
  __shared__ unsigned short VL[2][128 * 32];   // 2 x 8 KB (chunk-swizzled)
  __shared__ unsigned short PL[4][16 * PSTR];  // 4 x 1.25 KB (per-wave P)

  const int tid = threadIdx.x;
  const int wave = tid >> 6, lane = tid & 63;
  const int l15 = lane & 15, quad = lane >> 4;

  const int xb = (int)blockIdx.x;  // 0..15: handles qb = xb and qb = 31-xb
  const int b = (int)(blockIdx.y >> 5), h = (int)(blockIdx.y & 31);
  const int hkv = h >> 2;

  const unsigned short* kbf = kbfg + (size_t)(b * HKV_ + hkv) * S_ * D_;
  const unsigned short* vtb = vtg + (size_t)(b * HKV_ + hkv) * D_ * S_;

  const f32x4 zero4 = {0.f, 0.f, 0.f, 0.f};
  const float NEG_INF = -__builtin_huge_valf();

  // ---- async staging of one K/Vt tile pair into buffer `buf` ----
  // K chunk swizzle: phys chunk pc of row kr holds logical pc^(kr&15).
  // V chunk swizzle: phys chunk pc of row dr holds logical pc^((dr>>1)&3).
  auto stage = [&](int kt, int buf) {
#pragma unroll
    for (int j = 0; j < 2; ++j) {
      int si = wave * 128 + j * 64 + lane;
      int kr = si >> 4, pc = si & 15;
      int lc = pc ^ (kr & 15);
      load_lds16(kbf + (size_t)(kt * 32 + kr) * D_ + lc * 8,
                 &KL[buf][(wave * 128 + j * 64) * 8]);
    }
#pragma unroll
    for (int j = 0; j < 2; ++j) {
      int si = wave * 128 + j * 64 + lane;
      int dr = si >> 2, pc = si & 3;
      int lc = pc ^ ((dr >> 1) & 3);
      load_lds16(vtb + (size_t)dr * S_ + kt * 32 + lc * 8,
                 &VL[buf][(wave * 128 + j * 64) * 8]);
    }
  };

  for (int ph = 0; ph < 2; ++ph) {
    const int qb = ph ? (31 - xb) : xb;
    const int qbase = qb * 64 + wave * 16;  // this wave's 16 q rows

    // Q fragments (A-layout), pre-scaled by COEF -> exp arg = 1 subtract.
    bf16x8 qf[4];
#pragma unroll
    for (int ch = 0; ch < 4; ++ch) {
      const float* p = qg + (size_t)(b * S_ + qbase + l15) * (H_ * D_) +
                       h * D_ + ch * 32 + quad * 8;
      f32x4 x0 = *(const f32x4*)p;
      f32x4 x1 = *(const f32x4*)(p + 4);
      bf16x8 t;
      t[0] = (__bf16)(x0[0] * COEF); t[1] = (__bf16)(x0[1] * COEF);
      t[2] = (__bf16)(x0[2] * COEF); t[3] = (__bf16)(x0[3] * COEF);
      t[4] = (__bf16)(x1[0] * COEF); t[5] = (__bf16)(x1[1] * COEF);
      t[6] = (__bf16)(x1[2] * COEF); t[7] = (__bf16)(x1[3] * COEF);
      qf[ch] = t;
    }

    f32x4 acc[8];
#pragma unroll
    for (int dt = 0; dt < 8; ++dt) acc[dt] = zero4;
    f32x4 mrow = {NEG_INF, NEG_INF, NEG_INF, NEG_INF};
    f32x4 lsum = zero4;   // lane-partial row sum; reduced once in epilogue
    float mmin = NEG_INF; // min_r(mrow), updated only in slow path

    const int nkt = qb * 2 + 2;  // always even

    stage(0, 0);
    __syncthreads();  // drains vmcnt: tile 0 resident

    // One k-tile body; CUR must be a literal so KL/VL bases are
    // compile-time LDS offsets (addr chains CSE across the unroll).
#define KITER(KT, CUR)                                                        \
  do {                                                                        \
    const int kt_ = (KT);                                                     \
    if (kt_ + 1 < nkt) stage(kt_ + 1, (CUR) ^ 1);                             \
    if (kt_ * 32 <= qbase + 15) {                                             \
      f32x4 sc[2] = {zero4, zero4};                                           \
      __builtin_amdgcn_s_setprio(1);                                          \
      _Pragma("unroll") for (int h2 = 0; h2 < 2; ++h2) {                      \
        const int row = h2 * 16 + l15;                                        \
        _Pragma("unroll") for (int ch = 0; ch < 4; ++ch) {                    \
          const int pc = (ch * 4 + quad) ^ l15; /* un-swizzle */              \
          u16x8 kf = *(const u16x8*)&KL[(CUR)][row * D_ + pc * 8];            \
          sc[h2] = MFMA16(qf[ch], __builtin_bit_cast(bf16x8, kf), sc[h2]);    \
        }                                                                     \
      }                                                                       \
      __builtin_amdgcn_s_setprio(0);                                          \
      const int kb0 = kt_ * 32;                                               \
      _Pragma("unroll") for (int h2 = 0; h2 < 2; ++h2) {                      \
        if (kb0 + h2 * 16 + 15 > qbase) {                                     \
          int kgp = kb0 + h2 * 16 + l15;                                      \
          _Pragma("unroll") for (int r = 0; r < 4; ++r) {                     \
            int qgp = qbase + quad * 4 + r;                                   \
            if (kgp > qgp) sc[h2][r] = NEG_INF;                               \
          }                                                                   \
        }                                                                     \
      }                                                                       \
      /* defer-max gate: max over all 8 scores vs mmin+THR (conservative) */  \
      {                                                                       \
        float t01 = fmaxf(fmaxf(sc[0][0], sc[1][0]),                          \
                          fmaxf(sc[0][1], sc[1][1]));                         \
        float t23 = fmaxf(fmaxf(sc[0][2], sc[1][2]),                          \
                          fmaxf(sc[0][3], sc[1][3]));                         \
        float dmax = fmaxf(t01, t23);                                         \
        if (!__all(dmax <= mmin + DEFER_THR)) {                               \
          f32x4 al;                                                           \
          _Pragma("unroll") for (int r = 0; r < 4; ++r) {                     \
            float mt = rowmax16(fmaxf(sc[0][r], sc[1][r]));                   \
            float mn = fmaxf(mrow[r], mt);                                    \
            al[r] = EXP2F(mrow[r] - mn);                                      \
            mrow[r] = mn;                                                     \
            lsum[r] *= al[r];                                                 \
          }                                                                   \
          _Pragma("unroll") for (int dt = 0; dt < 8; ++dt)                    \
              _Pragma("unroll") for (int r = 0; r < 4; ++r)                   \
                  acc[dt][r] *= al[r];                                        \
          mmin = fminf(fminf(mrow[0], mrow[1]), fminf(mrow[2], mrow[3]));     \
        }                                                                     \
      }                                                                       \
      /* shared P computation (P bounded by 2^THR = 256) */                   \
      _Pragma("unroll") for (int r = 0; r < 4; ++r) {                         \
        float p0 = EXP2F(sc[0][r] - mrow[r]);                                 \
        float p1 = EXP2F(sc[1][r] - mrow[r]);                                 \
        sc[0][r] = p0;                                                        \
        sc[1][r] = p1;                                                        \
        lsum[r] += p0 + p1;                                                   \
      }                                                                       \
      /* P: C-layout -> LDS bf16 (even lanes pack pairs via quad_perm) */     \
      _Pragma("unroll") for (int h2 = 0; h2 < 2; ++h2)                        \
          _Pragma("unroll") for (int r = 0; r < 4; ++r) {                     \
        float mine = sc[h2][r];                                               \
        float nb = dppf<0xB1>(mine);                                          \
        if (!(l15 & 1)) {                                                     \
          bf16x2 pk;                                                          \
          pk[0] = (__bf16)mine;                                               \
          pk[1] = (__bf16)nb;                                                 \
          *(bf16x2*)&PL[wave][(quad * 4 + r) * PSTR + h2 * 16 + l15] = pk;    \
        }                                                                     \
      }                                                                       \
      /* PV: A = P (A-layout from LDS), B = Vt (swizzled chunks) */           \
      {                                                                       \
        u16x8 pf = *(const u16x8*)&PL[wave][l15 * PSTR + quad * 8];           \
        bf16x8 pb = __builtin_bit_cast(bf16x8, pf);                           \
        const int vsw = (quad ^ ((l15 >> 1) & 3)) * 8;                        \
        __builtin_amdgcn_s_setprio(1);                                        \
        _Pragma("unroll") for (int dt = 0; dt < 8; ++dt) {                    \
          u16x8 vf = *(const u16x8*)&VL[(CUR)][(dt * 16 + l15) * 32 + vsw];   \
          acc[dt] = MFMA16(pb, __builtin_bit_cast(bf16x8, vf), acc[dt]);      \
        }                                                                     \
        __builtin_amdgcn_s_setprio(0);                                        \
      }                                                                       \
    }                                                                         \
    __syncthreads(); /* drains vmcnt (next tile resident) + publishes bufs */ \
  } while (0)

    for (int kt = 0; kt < nkt; kt += 2) {
      KITER(kt, 0);
      KITER(kt + 1, 1);
    }
#undef KITER

    // ---- epilogue: reduce lane-partial sums once, O /= l, store fp32 ----
    f32x4 inv;
#pragma unroll
    for (int r = 0; r < 4; ++r) inv[r] = 1.0f / rowsum16(lsum[r]);
#pragma unroll
    for (int dt = 0; dt < 8; ++dt)
#pragma unroll
      for (int r = 0; r < 4; ++r)
        outg[(size_t)(b * S_ + qbase + quad * 4 + r) * (H_ * D_) +
             h * D_ + dt * 16 + l15] = acc[dt][r] * inv[r];
  }
}

extern "C" void kernel_launch(void* const* d_in, const int* in_sizes, int n_in,
                              void* d_out, int out_size, void* d_ws,
                              size_t ws_size, hipStream_t stream) {
  const float* q = (const float*)d_in[0];
  const float* k = (const float*)d_in[1];
  const float* v = (const float*)d_in[2];
  float* out = (float*)d_out;
  unsigned short* kws = (unsigned short*)d_ws;               // 8 MB Kbf
  unsigned short* vtws = kws + (size_t)B_ * HKV_ * S_ * D_;  // 8 MB Vt

  k_convert_kernel<<<(B_ * S_ * HKV_ * D_ / 8) / 256, 256, 0, stream>>>(k, kws);

  dim3 g1(S_ / 64, D_ / 32, B_ * HKV_);
  vt_transpose_kernel<<<g1, 256, 0, stream>>>(v, vtws);

  dim3 g2(16, B_ * H_);  // 16 x 64 = 1024 uniform blocks (68 k-iters each)
  attn_kernel<<<g2, 256, 0, stream>>>(q, kws, vtws, out);
}

// Round 5
// 233.230 us; speedup vs baseline: 1.5534x; 1.0327x over previous
//
#include <hip/hip_runtime.h>

// Causal GQA prefill attention, flash-style, bf16 MFMA / fp32 softmax.
// B=2, S=2048, H=32, HKV=8, D=128, G=4.
// Prepass 1: K fp32 -> Kbf bf16 [b][hkv][S][D]      (d_ws +0,   8 MB)
// Prepass 2: V fp32 -> Vt  bf16 [b][hkv][D][S]      (d_ws +8MB, 8 MB)
// Main: 1024 blocks = 16 causal pairs (qb=x, qb=31-x) x 64 bh.
// Round 5 (this): SWAPPED QK^T. MFMA16(kf,qf) flips C-layout to
//   (row=k=quad*4+r, col=q=l15): each lane's 8 scores belong to ONE
//   q-row (l15). mrow/lsum become scalars (-6 VGPR), gate is exact
//   per-row, slow path is 2 shuffles (was 16 DPP), P-repack is 2x
//   ds_write_b64 of (__bf16) casts (no DPP, no exec masks). alpha/inv
//   redistributed to acc rows (quad*4+r) via 4 ds_bpermute.
//   PSTR 40->36 (72B rows: 8B-aligned b64s, <=4-way banks).

#define B_   2
#define S_   2048
#define H_   32
#define HKV_ 8
#define D_   128
#define SCALEF 0.08838834764831845f
#define COEF  (SCALEF * 1.44269504088896340736f)   // scale * log2(e)
#define DEFER_THR 8.0f                             // log2-domain defer-max

typedef float          f32x4 __attribute__((ext_vector_type(4)));
typedef __bf16         bf16x4 __attribute__((ext_vector_type(4)));
typedef __bf16         bf16x8 __attribute__((ext_vector_type(8)));
typedef unsigned short u16x8 __attribute__((ext_vector_type(8)));

#define MFMA16(a, b, c) __builtin_amdgcn_mfma_f32_16x16x32_bf16((a), (b), (c), 0, 0, 0)

#if defined(__has_builtin)
#if __has_builtin(__builtin_amdgcn_exp2f)
#define EXP2F(x) __builtin_amdgcn_exp2f(x)
#endif
#endif
#ifndef EXP2F
#define EXP2F(x) exp2f(x)
#endif

static __device__ __forceinline__ unsigned short f2bf(float f) {
  unsigned int u = __builtin_bit_cast(unsigned int, f);
  u = (u + 0x7fffu + ((u >> 16) & 1u)) >> 16;   // RNE; inputs finite
  return (unsigned short)u;
}

// async global->LDS, 16B per lane; lds dest = wave-uniform base + lane*16.
static __device__ __forceinline__ void load_lds16(const void* g, void* l) {
  __builtin_amdgcn_global_load_lds(
      (const __attribute__((address_space(1))) void*)g,
      (__attribute__((address_space(3))) void*)l, 16, 0, 0);
}

// lane^16 exchange (DS pipe, within 32-lane halves): BitMode xor=16.
static __device__ __forceinline__ float swz_x16(float v) {
  return __builtin_bit_cast(
      float, __builtin_amdgcn_ds_swizzle(__builtin_bit_cast(int, v), 0x401F));
}
// generic pull from lane (byteaddr/4): full 64-lane crossbar.
static __device__ __forceinline__ float bperm_f(int byteaddr, float v) {
  return __builtin_bit_cast(
      float,
      __builtin_amdgcn_ds_bpermute(byteaddr, __builtin_bit_cast(int, v)));
}

// ------------- Prepass 1: K fp32 -> bf16 [b][hkv][S][D] -------------
__global__ __launch_bounds__(256) void k_convert_kernel(
    const float* __restrict__ k, unsigned short* __restrict__ kbf) {
  int t = blockIdx.x * 256 + threadIdx.x;
  int o = t * 8;                       // output-linear index
  int d = o & (D_ - 1);
  int s = (o >> 7) & (S_ - 1);
  int bh = o >> 18;                    // 0..15
  int b = bh >> 3, hkv = bh & 7;
  const float* src = k + (size_t)(b * S_ + s) * (HKV_ * D_) + hkv * D_ + d;
  f32x4 x0 = *(const f32x4*)src;
  f32x4 x1 = *(const f32x4*)(src + 4);
  u16x8 w;
  w[0] = f2bf(x0[0]); w[1] = f2bf(x0[1]); w[2] = f2bf(x0[2]); w[3] = f2bf(x0[3]);
  w[4] = f2bf(x1[0]); w[5] = f2bf(x1[1]); w[6] = f2bf(x1[2]); w[7] = f2bf(x1[3]);
  *(u16x8*)(kbf + o) = w;
}

// ------------- Prepass 2: V -> Vt (bf16, [b][hkv][D][S]) -------------
__global__ __launch_bounds__(256) void vt_transpose_kernel(
    const float* __restrict__ v, unsigned short* __restrict__ vt) {
  __shared__ float tile[32][65];  // +1 pad: conflict-free
  const int tid = threadIdx.x;
  const int s0 = blockIdx.x * 64;   // 32 s-tiles
  const int d0 = blockIdx.y * 32;   // 4 d-tiles
  const int bh = blockIdx.z;        // 16 (b*8+hkv)
  const float* src = v + (size_t)(bh >> 3) * S_ * (HKV_ * D_) + (bh & 7) * D_;
#pragma unroll
  for (int it = 0; it < 8; ++it) {
    int idx = it * 256 + tid;
    int sl = idx >> 5, dl = idx & 31;  // coalesced along d
    tile[dl][sl] = src[(size_t)(s0 + sl) * (HKV_ * D_) + d0 + dl];
  }
  __syncthreads();
  unsigned int* dst = (unsigned int*)vt;
#pragma unroll
  for (int it = 0; it < 4; ++it) {
    int idx = it * 256 + tid;
    int dl = idx >> 5, sp = idx & 31;
    unsigned int w = (unsigned int)f2bf(tile[dl][2 * sp]) |
                     ((unsigned int)f2bf(tile[dl][2 * sp + 1]) << 16);
    dst[(((size_t)bh * D_ + d0 + dl) * S_ + s0 + 2 * sp) >> 1] = w;
  }
}

// ------------- Main attention kernel -------------
#define PSTR 36  // PL row stride in shorts (72 B: 8B-aligned b64s, 18 banks)

__global__ __launch_bounds__(256, 4) void attn_kernel(
    const float* __restrict__ qg, const unsigned short* __restrict__ kbfg,
    const unsigned short* __restrict__ vtg, float* __restrict__ outg) {
  __shared__ unsigned short KL[2][32 * 128];   // 2 x 8 KB
  __shared__ unsigned short VL[2][128 * 32];   // 2 x 8 KB (chunk-swizzled)
  __shared__ unsigned short PL[4][16 * PSTR];  // 4 x 1.125 KB (per-wave P)

  const int tid = threadIdx.x;
  const int wave = tid >> 6, lane = tid & 63;
  const int l15 = lane & 15, quad = lane >> 4;
  const int a32 = ((lane ^ 32) << 2);  // bpermute addr: lane+-32 partner
  const int rowa = quad << 4;          // bpermute addr base: row quad*4

  const int xb = (int)blockIdx.x;  // 0..15: handles qb = xb and qb = 31-xb
  const int b = (int)(blockIdx.y >> 5), h = (int)(blockIdx.y & 31);
  const int hkv = h >> 2;

  const unsigned short* kbf = kbfg + (size_t)(b * HKV_ + hkv) * S_ * D_;
  const unsigned short* vtb = vtg + (size_t)(b * HKV_ + hkv) * D_ * S_;

  const f32x4 zero4 = {0.f, 0.f, 0.f, 0.f};
  const float NEG_INF = -__builtin_huge_valf();

  // ---- async staging of one K/Vt tile pair into buffer `buf` ----
  // K chunk swizzle: phys chunk pc of row kr holds logical pc^(kr&15).
  // V chunk swizzle: phys chunk pc of row dr holds logical pc^((dr>>1)&3).
  auto stage = [&](int kt, int buf) {
#pragma unroll
    for (int j = 0; j < 2; ++j) {
      int si = wave * 128 + j * 64 + lane;
      int kr = si >> 4, pc = si & 15;
      int lc = pc ^ (kr & 15);
      load_lds16(kbf + (size_t)(kt * 32 + kr) * D_ + lc * 8,
                 &KL[buf][(wave * 128 + j * 64) * 8]);
    }
#pragma unroll
    for (int j = 0; j < 2; ++j) {
      int si = wave * 128 + j * 64 + lane;
      int dr = si >> 2, pc = si & 3;
      int lc = pc ^ ((dr >> 1) & 3);
      load_lds16(vtb + (size_t)dr * S_ + kt * 32 + lc * 8,
                 &VL[buf][(wave * 128 + j * 64) * 8]);
    }
  };

  for (int ph = 0; ph < 2; ++ph) {
    const int qb = ph ? (31 - xb) : xb;
    const int qbase = qb * 64 + wave * 16;  // this wave's 16 q rows
    const int qgp = qbase + l15;            // this lane's q-row (swapped C)

    // Q fragments (A/B-layout identical), pre-scaled by COEF.
    bf16x8 qf[4];
#pragma unroll
    for (int ch = 0; ch < 4; ++ch) {
      const float* p = qg + (size_t)(b * S_ + qbase + l15) * (H_ * D_) +
                       h * D_ + ch * 32 + quad * 8;
      f32x4 x0 = *(const f32x4*)p;
      f32x4 x1 = *(const f32x4*)(p + 4);
      bf16x8 t;
      t[0] = (__bf16)(x0[0] * COEF); t[1] = (__bf16)(x0[1] * COEF);
      t[2] = (__bf16)(x0[2] * COEF); t[3] = (__bf16)(x0[3] * COEF);
      t[4] = (__bf16)(x1[0] * COEF); t[5] = (__bf16)(x1[1] * COEF);
      t[6] = (__bf16)(x1[2] * COEF); t[7] = (__bf16)(x1[3] * COEF);
      qf[ch] = t;
    }

    f32x4 acc[8];
#pragma unroll
    for (int dt = 0; dt < 8; ++dt) acc[dt] = zero4;
    float mrow = NEG_INF;  // running max of row q=l15 (scalar!)
    float lsum = 0.f;      // lane-partial sum of row q=l15 over own k-cols

    const int nkt = qb * 2 + 2;  // always even

    stage(0, 0);
    __syncthreads();  // drains vmcnt: tile 0 resident

    // One k-tile body; CUR literal so KL/VL bases are compile-time offsets.
    // Swapped QK^T: sc[h2][r] = S[k = kb0+h2*16+quad*4+r][q = l15].
#define KITER(KT, CUR)                                                        \
  do {                                                                        \
    const int kt_ = (KT);                                                     \
    if (kt_ + 1 < nkt) stage(kt_ + 1, (CUR) ^ 1);                             \
    if (kt_ * 32 <= qbase + 15) {                                             \
      f32x4 sc[2] = {zero4, zero4};                                           \
      __builtin_amdgcn_s_setprio(1);                                          \
      _Pragma("unroll") for (int h2 = 0; h2 < 2; ++h2) {                      \
        const int row = h2 * 16 + l15;                                        \
        _Pragma("unroll") for (int ch = 0; ch < 4; ++ch) {                    \
          const int pc = (ch * 4 + quad) ^ l15; /* un-swizzle */              \
          u16x8 kf = *(const u16x8*)&KL[(CUR)][row * D_ + pc * 8];            \
          sc[h2] = MFMA16(__builtin_bit_cast(bf16x8, kf), qf[ch], sc[h2]);    \
        }                                                                     \
      }                                                                       \
      __builtin_amdgcn_s_setprio(0);                                          \
      const int kb0 = kt_ * 32;                                               \
      /* causal mask: k = kb0+h2*16+quad*4+r vs q = qgp (boundary only) */    \
      _Pragma("unroll") for (int h2 = 0; h2 < 2; ++h2) {                      \
        if (kb0 + h2 * 16 + 15 > qbase) {                                     \
          int kb2 = kb0 + h2 * 16 + quad * 4;                                 \
          _Pragma("unroll") for (int r = 0; r < 4; ++r) {                     \
            if (kb2 + r > qgp) sc[h2][r] = NEG_INF;                           \
          }                                                                   \
        }                                                                     \
      }                                                                       \
      /* defer-max: lane's 8 scores are all row l15 -> exact scalar gate */   \
      float l8 = fmaxf(fmaxf(fmaxf(sc[0][0], sc[0][1]),                       \
                             fmaxf(sc[0][2], sc[0][3])),                      \
                       fmaxf(fmaxf(sc[1][0], sc[1][1]),                       \
                             fmaxf(sc[1][2], sc[1][3])));                     \
      if (!__all(l8 <= mrow + DEFER_THR)) {                                   \
        float t = fmaxf(l8, swz_x16(l8));  /* cross-quad row max */           \
        t = fmaxf(t, bperm_f(a32, t));                                        \
        float mn = fmaxf(mrow, t);                                            \
        float al = EXP2F(mrow - mn);                                          \
        mrow = mn;                                                            \
        lsum *= al;                                                           \
        f32x4 av; /* alpha for acc rows quad*4+r, from lanes r' = row */      \
        _Pragma("unroll") for (int r = 0; r < 4; ++r)                         \
            av[r] = bperm_f(rowa + (r << 2), al);                             \
        _Pragma("unroll") for (int dt = 0; dt < 8; ++dt)                      \
            _Pragma("unroll") for (int r = 0; r < 4; ++r)                     \
                acc[dt][r] *= av[r];                                          \
      }                                                                       \
      /* shared P computation (P bounded by 2^THR = 256) */                   \
      _Pragma("unroll") for (int h2 = 0; h2 < 2; ++h2)                        \
          _Pragma("unroll") for (int r = 0; r < 4; ++r)                       \
              sc[h2][r] = EXP2F(sc[h2][r] - mrow);                            \
      lsum += ((sc[0][0] + sc[0][1]) + (sc[0][2] + sc[0][3])) +               \
              ((sc[1][0] + sc[1][1]) + (sc[1][2] + sc[1][3]));                \
      /* P -> PL row q=l15, cols h2*16+quad*4+{0..3}: 2x ds_write_b64 */      \
      {                                                                       \
        bf16x4 w0, w1;                                                        \
        w0[0] = (__bf16)sc[0][0]; w0[1] = (__bf16)sc[0][1];                   \
        w0[2] = (__bf16)sc[0][2]; w0[3] = (__bf16)sc[0][3];                   \
        w1[0] = (__bf16)sc[1][0]; w1[1] = (__bf16)sc[1][1];                   \
        w1[2] = (__bf16)sc[1][2]; w1[3] = (__bf16)sc[1][3];                   \
        *(bf16x4*)&PL[wave][l15 * PSTR + quad * 4] = w0;                      \
        *(bf16x4*)&PL[wave][l15 * PSTR + 16 + quad * 4] = w1;                 \
      }                                                                       \
      /* PV: A = P rows q=l15, k=quad*8+j (two 8B-aligned b64 reads) */       \
      {                                                                       \
        bf16x4 p0 = *(const bf16x4*)&PL[wave][l15 * PSTR + quad * 8];         \
        bf16x4 p1 = *(const bf16x4*)&PL[wave][l15 * PSTR + quad * 8 + 4];     \
        bf16x8 pb = __builtin_shufflevector(p0, p1, 0, 1, 2, 3, 4, 5, 6, 7);  \
        const int vsw = (quad ^ ((l15 >> 1) & 3)) * 8;                        \
        __builtin_amdgcn_s_setprio(1);                                        \
        _Pragma("unroll") for (int dt = 0; dt < 8; ++dt) {                    \
          u16x8 vf = *(const u16x8*)&VL[(CUR)][(dt * 16 + l15) * 32 + vsw];   \
          acc[dt] = MFMA16(pb, __builtin_bit_cast(bf16x8, vf), acc[dt]);      \
        }                                                                     \
        __builtin_amdgcn_s_setprio(0);                                        \
      }                                                                       \
    }                                                                         \
    __syncthreads(); /* drains vmcnt (next tile resident) + publishes bufs */ \
  } while (0)

    for (int kt = 0; kt < nkt; kt += 2) {
      KITER(kt, 0);
      KITER(kt + 1, 1);
    }
#undef KITER

    // ---- epilogue: row sum via butterfly, redistribute inv to acc rows ----
    float s = lsum;
    s += swz_x16(s);
    s += bperm_f(a32, s);
    float linv = 1.0f / s;  // valid at every lane for row q=l15
    f32x4 inv;
#pragma unroll
    for (int r = 0; r < 4; ++r) inv[r] = bperm_f(rowa + (r << 2), linv);
#pragma unroll
    for (int dt = 0; dt < 8; ++dt)
#pragma unroll
      for (int r = 0; r < 4; ++r)
        outg[(size_t)(b * S_ + qbase + quad * 4 + r) * (H_ * D_) +
             h * D_ + dt * 16 + l15] = acc[dt][r] * inv[r];
  }
}

extern "C" void kernel_launch(void* const* d_in, const int* in_sizes, int n_in,
                              void* d_out, int out_size, void* d_ws,
                              size_t ws_size, hipStream_t stream) {
  const float* q = (const float*)d_in[0];
  const float* k = (const float*)d_in[1];
  const float* v = (const float*)d_in[2];
  float* out = (float*)d_out;
  unsigned short* kws = (unsigned short*)d_ws;               // 8 MB Kbf
  unsigned short* vtws = kws + (size_t)B_ * HKV_ * S_ * D_;  // 8 MB Vt

  k_convert_kernel<<<(B_ * S_ * HKV_ * D_ / 8) / 256, 256, 0, stream>>>(k, kws);

  dim3 g1(S_ / 64, D_ / 32, B_ * HKV_);
  vt_transpose_kernel<<<g1, 256, 0, stream>>>(v, vtws);

  dim3 g2(16, B_ * H_);  // 16 x 64 = 1024 uniform blocks (68 k-iters each)
  attn_kernel<<<g2, 256, 0, stream>>>(q, kws, vtws, out);
}

// Round 6
// 228.187 us; speedup vs baseline: 1.5877x; 1.0221x over previous
//
#include <hip/hip_runtime.h>

// Causal GQA prefill attention, flash-style, bf16 MFMA / fp32 softmax.
// B=2, S=2048, H=32, HKV=8, D=128, G=4.
// Prepass 1: K fp32 -> Kbf bf16 [b][hkv][S][D]      (d_ws +0,   8 MB)
// Prepass 2: V fp32 -> Vt  bf16 [b][hkv][D][S]      (d_ws +8MB, 8 MB)
// Round 5: swapped QK^T (softmax rows lane-local) -> attn 120 us,
//   VALU 37, Mfma 25, bank-conflicts 0. ~38% cycles both-pipes-idle.
// Round 6 (this):
//   - XCD-locality block remap: xcd=id&7 owns bhkv groups {2x,2x+1}
//     (4 MB K/V = its L2). FETCH showed 5.6x K/V HBM re-fetch before.
//   - counted-vmcnt loop: stage(k+1); vmcnt(4); s_barrier; compute(k);
//     s_barrier. No vmcnt(0) drain in steady state (T4); stage stays in
//     flight across barriers. WAR-safe: buf (k+1)&1 last read in
//     compute(k-1), sealed by the post-compute barrier.

#define B_   2
#define S_   2048
#define H_   32
#define HKV_ 8
#define D_   128
#define SCALEF 0.08838834764831845f
#define COEF  (SCALEF * 1.44269504088896340736f)   // scale * log2(e)
#define DEFER_THR 8.0f                             // log2-domain defer-max

typedef float          f32x4 __attribute__((ext_vector_type(4)));
typedef __bf16         bf16x4 __attribute__((ext_vector_type(4)));
typedef __bf16         bf16x8 __attribute__((ext_vector_type(8)));
typedef unsigned short u16x8 __attribute__((ext_vector_type(8)));

#define MFMA16(a, b, c) __builtin_amdgcn_mfma_f32_16x16x32_bf16((a), (b), (c), 0, 0, 0)

#if defined(__has_builtin)
#if __has_builtin(__builtin_amdgcn_exp2f)
#define EXP2F(x) __builtin_amdgcn_exp2f(x)
#endif
#endif
#ifndef EXP2F
#define EXP2F(x) exp2f(x)
#endif

static __device__ __forceinline__ unsigned short f2bf(float f) {
  unsigned int u = __builtin_bit_cast(unsigned int, f);
  u = (u + 0x7fffu + ((u >> 16) & 1u)) >> 16;   // RNE; inputs finite
  return (unsigned short)u;
}

// async global->LDS, 16B per lane; lds dest = wave-uniform base + lane*16.
static __device__ __forceinline__ void load_lds16(const void* g, void* l) {
  __builtin_amdgcn_global_load_lds(
      (const __attribute__((address_space(1))) void*)g,
      (__attribute__((address_space(3))) void*)l, 16, 0, 0);
}

// lane^16 exchange (DS pipe, within 32-lane halves): BitMode xor=16.
static __device__ __forceinline__ float swz_x16(float v) {
  return __builtin_bit_cast(
      float, __builtin_amdgcn_ds_swizzle(__builtin_bit_cast(int, v), 0x401F));
}
// generic pull from lane (byteaddr/4): full 64-lane crossbar.
static __device__ __forceinline__ float bperm_f(int byteaddr, float v) {
  return __builtin_bit_cast(
      float,
      __builtin_amdgcn_ds_bpermute(byteaddr, __builtin_bit_cast(int, v)));
}

// ------------- Prepass 1: K fp32 -> bf16 [b][hkv][S][D] -------------
__global__ __launch_bounds__(256) void k_convert_kernel(
    const float* __restrict__ k, unsigned short* __restrict__ kbf) {
  int t = blockIdx.x * 256 + threadIdx.x;
  int o = t * 8;                       // output-linear index
  int d = o & (D_ - 1);
  int s = (o >> 7) & (S_ - 1);
  int bh = o >> 18;                    // 0..15
  int b = bh >> 3, hkv = bh & 7;
  const float* src = k + (size_t)(b * S_ + s) * (HKV_ * D_) + hkv * D_ + d;
  f32x4 x0 = *(const f32x4*)src;
  f32x4 x1 = *(const f32x4*)(src + 4);
  u16x8 w;
  w[0] = f2bf(x0[0]); w[1] = f2bf(x0[1]); w[2] = f2bf(x0[2]); w[3] = f2bf(x0[3]);
  w[4] = f2bf(x1[0]); w[5] = f2bf(x1[1]); w[6] = f2bf(x1[2]); w[7] = f2bf(x1[3]);
  *(u16x8*)(kbf + o) = w;
}

// ------------- Prepass 2: V -> Vt (bf16, [b][hkv][D][S]) -------------
__global__ __launch_bounds__(256) void vt_transpose_kernel(
    const float* __restrict__ v, unsigned short* __restrict__ vt) {
  __shared__ float tile[32][65];  // +1 pad: conflict-free
  const int tid = threadIdx.x;
  const int s0 = blockIdx.x * 64;   // 32 s-tiles
  const int d0 = blockIdx.y * 32;   // 4 d-tiles
  const int bh = blockIdx.z;        // 16 (b*8+hkv)
  const float* src = v + (size_t)(bh >> 3) * S_ * (HKV_ * D_) + (bh & 7) * D_;
#pragma unroll
  for (int it = 0; it < 8; ++it) {
    int idx = it * 256 + tid;
    int sl = idx >> 5, dl = idx & 31;  // coalesced along d
    tile[dl][sl] = src[(size_t)(s0 + sl) * (HKV_ * D_) + d0 + dl];
  }
  __syncthreads();
  unsigned int* dst = (unsigned int*)vt;
#pragma unroll
  for (int it = 0; it < 4; ++it) {
    int idx = it * 256 + tid;
    int dl = idx >> 5, sp = idx & 31;
    unsigned int w = (unsigned int)f2bf(tile[dl][2 * sp]) |
                     ((unsigned int)f2bf(tile[dl][2 * sp + 1]) << 16);
    dst[(((size_t)bh * D_ + d0 + dl) * S_ + s0 + 2 * sp) >> 1] = w;
  }
}

// ------------- Main attention kernel -------------
#define PSTR 36  // PL row stride in shorts (72 B: 8B-aligned b64s, 18 banks)

__global__ __launch_bounds__(256, 4) void attn_kernel(
    const float* __restrict__ qg, const unsigned short* __restrict__ kbfg,
    const unsigned short* __restrict__ vtg, float* __restrict__ outg) {
  __shared__ unsigned short KL[2][32 * 128];   // 2 x 8 KB
  __shared__ unsigned short VL[2][128 * 32];   // 2 x 8 KB (chunk-swizzled)
  __shared__ unsigned short PL[4][16 * PSTR];  // 4 x 1.125 KB (per-wave P)

  const int tid = threadIdx.x;
  const int wave = tid >> 6, lane = tid & 63;
  const int l15 = lane & 15, quad = lane >> 4;
  const int a32 = ((lane ^ 32) << 2);  // bpermute addr: lane+-32 partner
  const int rowa = quad << 4;          // bpermute addr base: row quad*4

  // XCD-locality remap: dispatch id round-robins xcd = id&7 (8 XCDs).
  // Give each XCD 2 bhkv groups (2 x 2 MB K/V = its 4 MB L2); all 128
  // of its resident blocks then share the same K/V.
  const int id = (int)blockIdx.x + 16 * (int)blockIdx.y;  // 0..1023
  const int xcd = id & 7, slot = id >> 3;                 // slot 0..127
  const int bhkv = xcd * 2 + (slot >> 6);
  const int inner = slot & 63;
  const int g = inner >> 4;         // 0..3 head-in-group
  const int xb = inner & 15;        // causal pair index
  const int b = bhkv >> 3, hkv = bhkv & 7;
  const int h = hkv * 4 + g;

  const unsigned short* kbf = kbfg + (size_t)(b * HKV_ + hkv) * S_ * D_;
  const unsigned short* vtb = vtg + (size_t)(b * HKV_ + hkv) * D_ * S_;

  const f32x4 zero4 = {0.f, 0.f, 0.f, 0.f};
  const float NEG_INF = -__builtin_huge_valf();

  // ---- async staging of one K/Vt tile pair into buffer `buf` ----
  // K chunk swizzle: phys chunk pc of row kr holds logical pc^(kr&15).
  // V chunk swizzle: phys chunk pc of row dr holds logical pc^((dr>>1)&3).
  // 4 global_load_lds per wave per stage (vmcnt counts these in order).
  auto stage = [&](int kt, int buf) {
#pragma unroll
    for (int j = 0; j < 2; ++j) {
      int si = wave * 128 + j * 64 + lane;
      int kr = si >> 4, pc = si & 15;
      int lc = pc ^ (kr & 15);
      load_lds16(kbf + (size_t)(kt * 32 + kr) * D_ + lc * 8,
                 &KL[buf][(wave * 128 + j * 64) * 8]);
    }
#pragma unroll
    for (int j = 0; j < 2; ++j) {
      int si = wave * 128 + j * 64 + lane;
      int dr = si >> 2, pc = si & 3;
      int lc = pc ^ ((dr >> 1) & 3);
      load_lds16(vtb + (size_t)dr * S_ + kt * 32 + lc * 8,
                 &VL[buf][(wave * 128 + j * 64) * 8]);
    }
  };

  for (int ph = 0; ph < 2; ++ph) {
    const int qb = ph ? (31 - xb) : xb;
    const int qbase = qb * 64 + wave * 16;  // this wave's 16 q rows
    const int qgp = qbase + l15;            // this lane's q-row (swapped C)

    // Q fragments (A/B-layout identical), pre-scaled by COEF.
    bf16x8 qf[4];
#pragma unroll
    for (int ch = 0; ch < 4; ++ch) {
      const float* p = qg + (size_t)(b * S_ + qbase + l15) * (H_ * D_) +
                       h * D_ + ch * 32 + quad * 8;
      f32x4 x0 = *(const f32x4*)p;
      f32x4 x1 = *(const f32x4*)(p + 4);
      bf16x8 t;
      t[0] = (__bf16)(x0[0] * COEF); t[1] = (__bf16)(x0[1] * COEF);
      t[2] = (__bf16)(x0[2] * COEF); t[3] = (__bf16)(x0[3] * COEF);
      t[4] = (__bf16)(x1[0] * COEF); t[5] = (__bf16)(x1[1] * COEF);
      t[6] = (__bf16)(x1[2] * COEF); t[7] = (__bf16)(x1[3] * COEF);
      qf[ch] = t;
    }

    f32x4 acc[8];
#pragma unroll
    for (int dt = 0; dt < 8; ++dt) acc[dt] = zero4;
    float mrow = NEG_INF;  // running max of row q=l15 (scalar)
    float lsum = 0.f;      // lane-partial sum of row q=l15 over own k-cols

    const int nkt = qb * 2 + 2;  // always even

    stage(0, 0);
    asm volatile("s_waitcnt vmcnt(0)" ::: "memory");
    __builtin_amdgcn_s_barrier();
    __builtin_amdgcn_sched_barrier(0);  // tile 0 resident everywhere

    // One k-tile body; CUR literal so KL/VL bases are compile-time offsets.
    // Sync per iter: stage(k+1); vmcnt(4) [stage(k) done, stage(k+1) in
    // flight]; s_barrier [buf k resident in all waves]; compute(k);
    // s_barrier [all reads of buf k done -> stage(k+2) may overwrite].
#define KITER(KT, CUR)                                                        \
  do {                                                                        \
    const int kt_ = (KT);                                                     \
    if (kt_ + 1 < nkt) {                                                      \
      stage(kt_ + 1, (CUR) ^ 1);                                              \
      asm volatile("s_waitcnt vmcnt(4)" ::: "memory");                        \
    } else {                                                                  \
      asm volatile("s_waitcnt vmcnt(0)" ::: "memory");                        \
    }                                                                         \
    __builtin_amdgcn_s_barrier();                                             \
    __builtin_amdgcn_sched_barrier(0);                                        \
    if (kt_ * 32 <= qbase + 15) {                                             \
      f32x4 sc[2] = {zero4, zero4};                                           \
      __builtin_amdgcn_s_setprio(1);                                          \
      _Pragma("unroll") for (int h2 = 0; h2 < 2; ++h2) {                      \
        const int row = h2 * 16 + l15;                                        \
        _Pragma("unroll") for (int ch = 0; ch < 4; ++ch) {                    \
          const int pc = (ch * 4 + quad) ^ l15; /* un-swizzle */              \
          u16x8 kf = *(const u16x8*)&KL[(CUR)][row * D_ + pc * 8];            \
          sc[h2] = MFMA16(__builtin_bit_cast(bf16x8, kf), qf[ch], sc[h2]);    \
        }                                                                     \
      }                                                                       \
      __builtin_amdgcn_s_setprio(0);                                          \
      const int kb0 = kt_ * 32;                                               \
      /* causal mask: k = kb0+h2*16+quad*4+r vs q = qgp (boundary only) */    \
      _Pragma("unroll") for (int h2 = 0; h2 < 2; ++h2) {                      \
        if (kb0 + h2 * 16 + 15 > qbase) {                                     \
          int kb2 = kb0 + h2 * 16 + quad * 4;                                 \
          _Pragma("unroll") for (int r = 0; r < 4; ++r) {                     \
            if (kb2 + r > qgp) sc[h2][r] = NEG_INF;                           \
          }                                                                   \
        }                                                                     \
      }                                                                       \
      /* defer-max: lane's 8 scores are all row l15 -> exact scalar gate */   \
      float l8 = fmaxf(fmaxf(fmaxf(sc[0][0], sc[0][1]),                       \
                             fmaxf(sc[0][2], sc[0][3])),                      \
                       fmaxf(fmaxf(sc[1][0], sc[1][1]),                       \
                             fmaxf(sc[1][2], sc[1][3])));                     \
      if (!__all(l8 <= mrow + DEFER_THR)) {                                   \
        float t = fmaxf(l8, swz_x16(l8));  /* cross-quad row max */           \
        t = fmaxf(t, bperm_f(a32, t));                                        \
        float mn = fmaxf(mrow, t);                                            \
        float al = EXP2F(mrow - mn);                                          \
        mrow = mn;                                                            \
        lsum *= al;                                                           \
        f32x4 av; /* alpha for acc rows quad*4+r, from lanes r' = row */      \
        _Pragma("unroll") for (int r = 0; r < 4; ++r)                         \
            av[r] = bperm_f(rowa + (r << 2), al);                             \
        _Pragma("unroll") for (int dt = 0; dt < 8; ++dt)                      \
            _Pragma("unroll") for (int r = 0; r < 4; ++r)                     \
                acc[dt][r] *= av[r];                                          \
      }                                                                       \
      /* shared P computation (P bounded by 2^THR = 256) */                   \
      _Pragma("unroll") for (int h2 = 0; h2 < 2; ++h2)                        \
          _Pragma("unroll") for (int r = 0; r < 4; ++r)                       \
              sc[h2][r] = EXP2F(sc[h2][r] - mrow);                            \
      lsum += ((sc[0][0] + sc[0][1]) + (sc[0][2] + sc[0][3])) +               \
              ((sc[1][0] + sc[1][1]) + (sc[1][2] + sc[1][3]));                \
      /* P -> PL row q=l15, cols h2*16+quad*4+{0..3}: 2x ds_write_b64 */      \
      {                                                                       \
        bf16x4 w0, w1;                                                        \
        w0[0] = (__bf16)sc[0][0]; w0[1] = (__bf16)sc[0][1];                   \
        w0[2] = (__bf16)sc[0][2]; w0[3] = (__bf16)sc[0][3];                   \
        w1[0] = (__bf16)sc[1][0]; w1[1] = (__bf16)sc[1][1];                   \
        w1[2] = (__bf16)sc[1][2]; w1[3] = (__bf16)sc[1][3];                   \
        *(bf16x4*)&PL[wave][l15 * PSTR + quad * 4] = w0;                      \
        *(bf16x4*)&PL[wave][l15 * PSTR + 16 + quad * 4] = w1;                 \
      }                                                                       \
      /* PV: A = P rows q=l15, k=quad*8+j (two 8B-aligned b64 reads) */       \
      {                                                                       \
        bf16x4 p0 = *(const bf16x4*)&PL[wave][l15 * PSTR + quad * 8];         \
        bf16x4 p1 = *(const bf16x4*)&PL[wave][l15 * PSTR + quad * 8 + 4];     \
        bf16x8 pb = __builtin_shufflevector(p0, p1, 0, 1, 2, 3, 4, 5, 6, 7);  \
        const int vsw = (quad ^ ((l15 >> 1) & 3)) * 8;                        \
        __builtin_amdgcn_s_setprio(1);                                        \
        _Pragma("unroll") for (int dt = 0; dt < 8; ++dt) {                    \
          u16x8 vf = *(const u16x8*)&VL[(CUR)][(dt * 16 + l15) * 32 + vsw];   \
          acc[dt] = MFMA16(pb, __builtin_bit_cast(bf16x8, vf), acc[dt]);      \
        }                                                                     \
        __builtin_amdgcn_s_setprio(0);                                        \
      }                                                                       \
    }                                                                         \
    __builtin_amdgcn_s_barrier(); /* reads of buf k done (WAR seal) */        \
    __builtin_amdgcn_sched_barrier(0);                                        \
  } while (0)

    for (int kt = 0; kt < nkt; kt += 2) {
      KITER(kt, 0);
      KITER(kt + 1, 1);
    }
#undef KITER

    // ---- epilogue: row sum via butterfly, redistribute inv to acc rows ----
    float s = lsum;
    s += swz_x16(s);
    s += bperm_f(a32, s);
    float linv = 1.0f / s;  // valid at every lane for row q=l15
    f32x4 inv;
#pragma unroll
    for (int r = 0; r < 4; ++r) inv[r] = bperm_f(rowa + (r << 2), linv);
#pragma unroll
    for (int dt = 0; dt < 8; ++dt)
#pragma unroll
      for (int r = 0; r < 4; ++r)
        outg[(size_t)(b * S_ + qbase + quad * 4 + r) * (H_ * D_) +
             h * D_ + dt * 16 + l15] = acc[dt][r] * inv[r];
  }
}

extern "C" void kernel_launch(void* const* d_in, const int* in_sizes, int n_in,
                              void* d_out, int out_size, void* d_ws,
                              size_t ws_size, hipStream_t stream) {
  const float* q = (const float*)d_in[0];
  const float* k = (const float*)d_in[1];
  const float* v = (const float*)d_in[2];
  float* out = (float*)d_out;
  unsigned short* kws = (unsigned short*)d_ws;               // 8 MB Kbf
  unsigned short* vtws = kws + (size_t)B_ * HKV_ * S_ * D_;  // 8 MB Vt

  k_convert_kernel<<<(B_ * S_ * HKV_ * D_ / 8) / 256, 256, 0, stream>>>(k, kws);

  dim3 g1(S_ / 64, D_ / 32, B_ * HKV_);
  vt_transpose_kernel<<<g1, 256, 0, stream>>>(v, vtws);

  dim3 g2(16, B_ * H_);  // 1024 blocks; XCD-locality remap inside kernel
  attn_kernel<<<g2, 256, 0, stream>>>(q, kws, vtws, out);
}